// Round 6
// baseline (161.350 us; speedup 1.0000x reference)
//
#include <hip/hip_runtime.h>

#define L_LEN   16384
#define P_DIM   512
#define CHUNK   32
#define NCHUNK  512        // L_LEN / CHUNK

#define KDIM    1024       // 2*P, re/im interleaved: k = 2p (re), 2p+1 (im)
#define NDIM    512
#define BM      32         // time rows per fused block
#define NSPLIT  2          // N halves per time tile
#define NBLK    (L_LEN / BM * NSPLIT)   // 1024 blocks -> 2 per CU

typedef __bf16 bf16_t;
typedef __bf16 bf16x8 __attribute__((ext_vector_type(8)));
typedef float  floatx4 __attribute__((ext_vector_type(4)));

__device__ __forceinline__ uint32_t pack_bf16(float a, float b) {
    bf16_t ha = (bf16_t)a, hb = (bf16_t)b;
    return (uint32_t)__builtin_bit_cast(unsigned short, ha)
         | ((uint32_t)__builtin_bit_cast(unsigned short, hb) << 16);
}

// Per-channel discretization constants: a = exp(lambda*step), B = (a-1)/lambda
__device__ __forceinline__ void ch_consts(float lam0, float lam1, float ls,
                                          float& ar, float& ai,
                                          float& br, float& bi) {
    float lr = -expf(lam0);               // Re(lambda) < 0
    float li = lam1;                      // Im(lambda)
    float s  = expf(ls);
    float er = expf(lr * s);
    ar = er * cosf(li * s);
    ai = er * sinf(li * s);
    float dr = ar - 1.0f, di = ai;
    float inv = 1.0f / (lr * lr + li * li);
    br = (dr * lr + di * li) * inv;
    bi = (di * lr - dr * li) * inv;
}

// Phase 1: per (chunk, channel-pair) local scan, zero init; write end states.
// Thread t handles channels 2t, 2t+1 via float2 loads. Bt pack fused in.
__global__ void __launch_bounds__(256) k_scan_ends(const float* __restrict__ u,
        const float* __restrict__ Lam, const float* __restrict__ lstep,
        const float* __restrict__ Vre, const float* __restrict__ Vim,
        float2* __restrict__ endv, bf16_t* __restrict__ Bt) {
    const int t = threadIdx.x;
    const int c = blockIdx.x;

    // Bt pack: Bt[j][2p]=V_re[j][p], Bt[j][2p+1]=-V_im[j][p]. idx covers 512*512/2.
    {
        int idx = c * 256 + t;
        float2 vr = ((const float2*)Vre)[idx];
        float2 vi = ((const float2*)Vim)[idx];
        ((uint2*)Bt)[idx] = make_uint2(pack_bf16(vr.x, -vi.x),
                                       pack_bf16(vr.y, -vi.y));
    }

    float4 lam4 = ((const float4*)Lam)[t];       // channels 2t, 2t+1
    float2 ls2  = ((const float2*)lstep)[t];
    float ar0, ai0, br0, bi0, ar1, ai1, br1, bi1;
    ch_consts(lam4.x, lam4.y, ls2.x, ar0, ai0, br0, bi0);
    ch_consts(lam4.z, lam4.w, ls2.y, ar1, ai1, br1, bi1);

    float xr0 = 0.f, xi0 = 0.f, xr1 = 0.f, xi1 = 0.f;
    const float2* up = (const float2*)(u + (size_t)c * CHUNK * P_DIM) + t;
    #pragma unroll 8
    for (int k = 0; k < CHUNK; ++k) {
        float2 uv = up[(size_t)k * (P_DIM / 2)];
        float nr0 = ar0 * xr0 - ai0 * xi0 + br0 * uv.x;
        float ni0 = ar0 * xi0 + ai0 * xr0 + bi0 * uv.x;
        float nr1 = ar1 * xr1 - ai1 * xi1 + br1 * uv.y;
        float ni1 = ar1 * xi1 + ai1 * xr1 + bi1 * uv.y;
        xr0 = nr0; xi0 = ni0; xr1 = nr1; xi1 = ni1;
    }
    ((float4*)endv)[c * 256 + t] = make_float4(xr0, xi0, xr1, xi1);
}

// Phase 2: Kogge-Stone carry scan over 512 chunk aggregates.
// Block = 2 channels x 512 chunks = 1024 threads; 256 blocks.
// carry[c] = state entering chunk c; A_chunk = a^CHUNK.
__global__ void __launch_bounds__(1024) k_carry(const float* __restrict__ Lam,
        const float* __restrict__ lstep, const float2* __restrict__ endv,
        float2* __restrict__ carry) {
    __shared__ float2 zl[NCHUNK * 2];
    const int tid = threadIdx.x;
    const int g = tid & 1;            // channel slot within block
    const int c = tid >> 1;           // chunk index 0..511
    const int p = blockIdx.x * 2 + g;

    float lr = -expf(Lam[2 * p + 0]);
    float li = Lam[2 * p + 1];
    float s  = expf(lstep[p]);
    float tt = s * (float)CHUNK;
    float er = expf(lr * tt);
    float Ar = er * cosf(li * tt);    // A = a^CHUNK
    float Ai = er * sinf(li * tt);

    float2 e = endv[(size_t)c * P_DIM + p];
    float zr = e.x, zi = e.y;
    zl[c * 2 + g] = make_float2(zr, zi);
    __syncthreads();
    for (int st = 1; st < NCHUNK; st <<= 1) {
        float tr = 0.f, ti = 0.f;
        if (c >= st) { float2 v = zl[(c - st) * 2 + g]; tr = v.x; ti = v.y; }
        __syncthreads();
        zr += Ar * tr - Ai * ti;
        zi += Ar * ti + Ai * tr;
        zl[c * 2 + g] = make_float2(zr, zi);
        float nAr = Ar * Ar - Ai * Ai;    // A^(2s)
        float nAi = 2.f * Ar * Ai;
        Ar = nAr; Ai = nAi;
        __syncthreads();
    }
    float2 cv = make_float2(0.f, 0.f);
    if (c > 0) cv = zl[(c - 1) * 2 + g];   // exclusive prefix
    carry[(size_t)c * P_DIM + p] = cv;
}

// Phase 3 (fused): 32-row scan from carry into a 64KB LDS A-tile, then GEMM
// M=32 x N=256 x K=1024 from LDS, B direct from L2-resident Bt, spike epilogue.
// Grid: 1024 blocks (512 time tiles x 2 N-halves) -> 2 blocks/CU, 4 waves/SIMD:
// one block's GEMM overlaps the other's latency-bound scan/stores.
// A-LDS swizzle at 16B-chunk granularity over 4 bits: slot (k, st) holds chunk
// (k, st ^ (k&15)) -> both ds_write and ds_read conflict-free (16-lane groups
// cover 16 distinct 16B slots).
__global__ void __launch_bounds__(512, 4) k_scan_gemm(const float* __restrict__ u,
        const float* __restrict__ Lam, const float* __restrict__ lstep,
        const float2* __restrict__ carry, const bf16_t* __restrict__ Bt,
        float* __restrict__ out) {
    __shared__ bf16_t As[BM * KDIM];   // 64 KB

    const int tid = threadIdx.x;       // 0..511
    const int bx  = blockIdx.x;
    const int c   = bx >> 1;           // time tile: rows 32c .. 32c+31
    const int nh  = bx & 1;            // N half: cols nh*256 .. +255

    // ---- scan phase: thread = channel p; u fully in regs (32 VGPR) ----
    {
        const int p = tid;
        float ar, ai, br, bi;
        ch_consts(Lam[2 * p + 0], Lam[2 * p + 1], lstep[p], ar, ai, br, bi);
        float2 cv = carry[(size_t)c * P_DIM + p];
        float xr = cv.x, xi = cv.y;
        const float* up = u + (size_t)c * BM * P_DIM + p;
        float ur[BM];
        #pragma unroll
        for (int k = 0; k < BM; ++k) ur[k] = up[(size_t)k * P_DIM];
        const int ct  = p >> 2;          // 16B chunk within row (0..127)
        const int sub = (p & 3) * 4;     // byte within chunk
        #pragma unroll
        for (int k = 0; k < BM; ++k) {
            float nr = ar * xr - ai * xi + br * ur[k];
            float ni = ar * xi + ai * xr + bi * ur[k];
            xr = nr; xi = ni;
            int st = ct ^ (k & 15);
            *(uint32_t*)((char*)As + (size_t)k * 2048 + st * 16 + sub)
                = pack_bf16(xr, xi);
        }
    }
    __syncthreads();

    // ---- GEMM phase: 8 waves, wave w -> N cols [nh*256 + 32w, +32) ----
    const int lane  = tid & 63;
    const int w     = tid >> 6;        // 0..7
    const int nbase = nh * 256 + w * 32;
    const int fr_m  = lane & 15;
    const int fr_g  = lane >> 4;

    floatx4 acc[2][2];
    #pragma unroll
    for (int i = 0; i < 2; ++i)
        #pragma unroll
        for (int j = 0; j < 2; ++j) {
            floatx4 z = {0.f, 0.f, 0.f, 0.f};
            acc[i][j] = z;
        }

    const bf16_t* Bw = Bt + (size_t)(nbase + fr_m) * KDIM + fr_g * 8;

    #pragma unroll
    for (int kt = 0; kt < KDIM; kt += 32) {
        bf16x8 af[2], bfv[2];
        #pragma unroll
        for (int j = 0; j < 2; ++j)
            bfv[j] = *(const bf16x8*)(Bw + (size_t)j * 16 * KDIM + kt);
        #pragma unroll
        for (int i = 0; i < 2; ++i) {
            int m  = i * 16 + fr_m;
            int cc = (kt >> 3) + fr_g;
            int sc = cc ^ (m & 15);
            af[i] = *(const bf16x8*)((const char*)As + (size_t)m * 2048 + sc * 16);
        }
        #pragma unroll
        for (int i = 0; i < 2; ++i)
            #pragma unroll
            for (int j = 0; j < 2; ++j)
                acc[i][j] = __builtin_amdgcn_mfma_f32_16x16x32_bf16(
                    af[i], bfv[j], acc[i][j], 0, 0, 0);
    }

    // Epilogue: C/D layout col=lane&15, row=(lane>>4)*4+reg (m89-verified).
    float* outb = out + (size_t)c * BM * NDIM;
    #pragma unroll
    for (int i = 0; i < 2; ++i)
        #pragma unroll
        for (int j = 0; j < 2; ++j)
            #pragma unroll
            for (int r = 0; r < 4; ++r) {
                int rr = i * 16 + fr_g * 4 + r;
                int cl = nbase + j * 16 + fr_m;
                float v = acc[i][j][r];
                outb[(size_t)rr * NDIM + cl] = (v > 1.0f) ? 1.0f : 0.0f;
            }
}

extern "C" void kernel_launch(void* const* d_in, const int* in_sizes, int n_in,
                              void* d_out, int out_size, void* d_ws, size_t ws_size,
                              hipStream_t stream) {
    (void)in_sizes; (void)n_in; (void)out_size; (void)ws_size;
    const float* u     = (const float*)d_in[0];
    const float* Lam   = (const float*)d_in[1];
    const float* lstep = (const float*)d_in[2];
    const float* Vre   = (const float*)d_in[3];
    const float* Vim   = (const float*)d_in[4];
    float* out = (float*)d_out;

    char* ws = (char*)d_ws;
    const size_t endv_bytes  = (size_t)NCHUNK * P_DIM * sizeof(float2);   // 2 MB
    const size_t carry_bytes = endv_bytes;                                // 2 MB
    float2* endv  = (float2*)(ws);
    float2* carry = (float2*)(ws + endv_bytes);
    bf16_t* Bt    = (bf16_t*)(ws + endv_bytes + carry_bytes);             // 1 MB

    hipLaunchKernelGGL(k_scan_ends, dim3(NCHUNK), dim3(256), 0, stream,
                       u, Lam, lstep, Vre, Vim, endv, Bt);
    hipLaunchKernelGGL(k_carry, dim3(P_DIM / 2), dim3(1024), 0, stream,
                       Lam, lstep, endv, carry);
    hipLaunchKernelGGL(k_scan_gemm, dim3(NBLK), dim3(512), 0, stream,
                       u, Lam, lstep, carry, Bt, out);
}

// Round 7
// 139.200 us; speedup vs baseline: 1.1591x; 1.1591x over previous
//
#include <hip/hip_runtime.h>

#define L_LEN   16384
#define P_DIM   512
#define CHUNK   32
#define NCHUNK  512        // L_LEN / CHUNK

#define KDIM    1024       // 2*P, re/im interleaved: k = 2p (re), 2p+1 (im)
#define NDIM    512
#define BM      128
#define BN      64
#define BK      64

typedef __bf16 bf16_t;
typedef __bf16 bf16x8 __attribute__((ext_vector_type(8)));
typedef float  floatx4 __attribute__((ext_vector_type(4)));

__device__ __forceinline__ uint32_t pack_bf16(float a, float b) {
    bf16_t ha = (bf16_t)a, hb = (bf16_t)b;
    return (uint32_t)__builtin_bit_cast(unsigned short, ha)
         | ((uint32_t)__builtin_bit_cast(unsigned short, hb) << 16);
}

// Per-channel discretization constants: a = exp(lambda*step), B = (a-1)/lambda
__device__ __forceinline__ void ch_consts(float lam0, float lam1, float ls,
                                          float& ar, float& ai,
                                          float& br, float& bi) {
    float lr = -expf(lam0);               // Re(lambda) < 0
    float li = lam1;                      // Im(lambda)
    float s  = expf(ls);
    float er = expf(lr * s);
    ar = er * cosf(li * s);
    ai = er * sinf(li * s);
    float dr = ar - 1.0f, di = ai;
    float inv = 1.0f / (lr * lr + li * li);
    br = (dr * lr + di * li) * inv;
    bi = (di * lr - dr * li) * inv;
}

// Phase 1: per (chunk, channel-pair) local scan, zero init; write end states.
// Thread t handles channels 2t, 2t+1 via float2 loads. Bt pack fused in.
__global__ void __launch_bounds__(256) k_scan_ends(const float* __restrict__ u,
        const float* __restrict__ Lam, const float* __restrict__ lstep,
        const float* __restrict__ Vre, const float* __restrict__ Vim,
        float2* __restrict__ endv, bf16_t* __restrict__ Bt) {
    const int t = threadIdx.x;
    const int c = blockIdx.x;

    // Bt pack: Bt[j][2p]=V_re[j][p], Bt[j][2p+1]=-V_im[j][p]. idx covers 512*512/2.
    {
        int idx = c * 256 + t;
        float2 vr = ((const float2*)Vre)[idx];
        float2 vi = ((const float2*)Vim)[idx];
        ((uint2*)Bt)[idx] = make_uint2(pack_bf16(vr.x, -vi.x),
                                       pack_bf16(vr.y, -vi.y));
    }

    float4 lam4 = ((const float4*)Lam)[t];       // channels 2t, 2t+1
    float2 ls2  = ((const float2*)lstep)[t];
    float ar0, ai0, br0, bi0, ar1, ai1, br1, bi1;
    ch_consts(lam4.x, lam4.y, ls2.x, ar0, ai0, br0, bi0);
    ch_consts(lam4.z, lam4.w, ls2.y, ar1, ai1, br1, bi1);

    float xr0 = 0.f, xi0 = 0.f, xr1 = 0.f, xi1 = 0.f;
    const float2* up = (const float2*)(u + (size_t)c * CHUNK * P_DIM) + t;
    #pragma unroll 8
    for (int k = 0; k < CHUNK; ++k) {
        float2 uv = up[(size_t)k * (P_DIM / 2)];
        float nr0 = ar0 * xr0 - ai0 * xi0 + br0 * uv.x;
        float ni0 = ar0 * xi0 + ai0 * xr0 + bi0 * uv.x;
        float nr1 = ar1 * xr1 - ai1 * xi1 + br1 * uv.y;
        float ni1 = ar1 * xi1 + ai1 * xr1 + bi1 * uv.y;
        xr0 = nr0; xi0 = ni0; xr1 = nr1; xi1 = ni1;
    }
    ((float4*)endv)[c * 256 + t] = make_float4(xr0, xi0, xr1, xi1);
}

// Phase 2: Kogge-Stone carry scan over 512 chunk aggregates.
// Block = 2 channels x 512 chunks = 1024 threads; 256 blocks.
// carry[c] = state entering chunk c; A_chunk = a^CHUNK.
__global__ void __launch_bounds__(1024) k_carry(const float* __restrict__ Lam,
        const float* __restrict__ lstep, const float2* __restrict__ endv,
        float2* __restrict__ carry) {
    __shared__ float2 zl[NCHUNK * 2];
    const int tid = threadIdx.x;
    const int g = tid & 1;            // channel slot within block
    const int c = tid >> 1;           // chunk index 0..511
    const int p = blockIdx.x * 2 + g;

    float lr = -expf(Lam[2 * p + 0]);
    float li = Lam[2 * p + 1];
    float s  = expf(lstep[p]);
    float tt = s * (float)CHUNK;
    float er = expf(lr * tt);
    float Ar = er * cosf(li * tt);    // A = a^CHUNK
    float Ai = er * sinf(li * tt);

    float2 e = endv[(size_t)c * P_DIM + p];
    float zr = e.x, zi = e.y;
    zl[c * 2 + g] = make_float2(zr, zi);
    __syncthreads();
    for (int st = 1; st < NCHUNK; st <<= 1) {
        float tr = 0.f, ti = 0.f;
        if (c >= st) { float2 v = zl[(c - st) * 2 + g]; tr = v.x; ti = v.y; }
        __syncthreads();
        zr += Ar * tr - Ai * ti;
        zi += Ar * ti + Ai * tr;
        zl[c * 2 + g] = make_float2(zr, zi);
        float nAr = Ar * Ar - Ai * Ai;    // A^(2s)
        float nAi = 2.f * Ar * Ai;
        Ar = nAr; Ai = nAi;
        __syncthreads();
    }
    float2 cv = make_float2(0.f, 0.f);
    if (c > 0) cv = zl[(c - 1) * 2 + g];   // exclusive prefix
    carry[(size_t)c * P_DIM + p] = cv;
}

// Phase 3: recompute local scan with carry init; write A bf16 row-major
// [t][1024], k interleaved -> one 8B store per step per channel-pair.
__global__ void __launch_bounds__(256) k_materialize(const float* __restrict__ u,
        const float* __restrict__ Lam, const float* __restrict__ lstep,
        const float2* __restrict__ carry, bf16_t* __restrict__ A) {
    const int t = threadIdx.x;
    const int c = blockIdx.x;

    float4 lam4 = ((const float4*)Lam)[t];
    float2 ls2  = ((const float2*)lstep)[t];
    float ar0, ai0, br0, bi0, ar1, ai1, br1, bi1;
    ch_consts(lam4.x, lam4.y, ls2.x, ar0, ai0, br0, bi0);
    ch_consts(lam4.z, lam4.w, ls2.y, ar1, ai1, br1, bi1);

    float4 cv = ((const float4*)carry)[c * 256 + t];
    float xr0 = cv.x, xi0 = cv.y, xr1 = cv.z, xi1 = cv.w;
    const float2* up = (const float2*)(u + (size_t)c * CHUNK * P_DIM) + t;
    uint2* Ap = (uint2*)(A + (size_t)c * CHUNK * KDIM) + t;   // 256 uint2 per row
    #pragma unroll 4
    for (int k = 0; k < CHUNK; ++k) {
        float2 uv = up[(size_t)k * (P_DIM / 2)];
        float nr0 = ar0 * xr0 - ai0 * xi0 + br0 * uv.x;
        float ni0 = ar0 * xi0 + ai0 * xr0 + bi0 * uv.x;
        float nr1 = ar1 * xr1 - ai1 * xi1 + br1 * uv.y;
        float ni1 = ar1 * xi1 + ai1 * xr1 + bi1 * uv.y;
        xr0 = nr0; xi0 = ni0; xr1 = nr1; xi1 = ni1;
        Ap[(size_t)k * 256] = make_uint2(pack_bf16(xr0, xi0),
                                         pack_bf16(xr1, xi1));
    }
}

// GEMM: out[m][n] = sum_k A[m][k]*Bt[n][k], spike threshold epilogue.
// 128x64 block tile, 4 waves each 64x32 (4x2 of 16x16x32 bf16 MFMA), BK=64.
// 2-phase double-buffered LDS (T3-lite): issue next tile's global_load_lds
// BEFORE computing current tile; single __syncthreads per K-step (its
// implicit vmcnt(0) lands after the MFMAs, so load latency hides under them).
// Staging: LINEAR LDS dest, INVERSE-swizzled global source, swizzled ds_read.
// LDS slot (row,sc) holds chunk (row, sc^(row&7)). 48 KB LDS -> 3 blocks/CU.
__global__ void __launch_bounds__(256, 3) k_gemm(const bf16_t* __restrict__ A,
        const bf16_t* __restrict__ Bt, float* __restrict__ out) {
    __shared__ uint4 As4[2 * BM * BK * 2 / 16];   // 2 x 1024 chunks, 32 KB
    __shared__ uint4 Bs4[2 * BN * BK * 2 / 16];   // 2 x  512 chunks, 16 KB

    const int tid  = threadIdx.x;
    const int lane = tid & 63;
    const int w    = tid >> 6;
    const int m0   = blockIdx.x * BM;
    const int n0   = blockIdx.y * BN;
    const int wm   = (w >> 1) * 64;   // 0 or 64
    const int wn   = (w & 1) * 32;    // 0 or 32

    const int fr_m = lane & 15;   // M/N index within 16x16 for A/B operands
    const int fr_g = lane >> 4;   // k-group (quad) 0..3

    floatx4 acc[4][2];
    #pragma unroll
    for (int i = 0; i < 4; ++i)
        #pragma unroll
        for (int j = 0; j < 2; ++j) {
            floatx4 z = {0.f, 0.f, 0.f, 0.f};
            acc[i][j] = z;
        }

    const bf16_t* Asrc = A  + (size_t)m0 * KDIM;
    const bf16_t* Bsrc = Bt + (size_t)n0 * KDIM;

    // Hoisted staging addresses. q = linear LDS chunk slot; source chunk
    // col = (q&7) ^ (row&7) so swizzled reads land right.
    const bf16_t* ga[4]; char* la[4];
    const bf16_t* gb[2]; char* lb[2];
    #pragma unroll
    for (int i = 0; i < 4; ++i) {
        int q   = i * 256 + tid;
        int row = q >> 3;
        int gc  = (q & 7) ^ (row & 7);
        ga[i] = Asrc + (size_t)row * KDIM + gc * 8;
        la[i] = (char*)As4 + (size_t)q * 16;
    }
    #pragma unroll
    for (int i = 0; i < 2; ++i) {
        int q   = i * 256 + tid;
        int row = q >> 3;
        int gc  = (q & 7) ^ (row & 7);
        gb[i] = Bsrc + (size_t)row * KDIM + gc * 8;
        lb[i] = (char*)Bs4 + (size_t)q * 16;
    }

    // Prologue: stage tile 0 into buffer 0 and drain.
    #pragma unroll
    for (int i = 0; i < 4; ++i)
        __builtin_amdgcn_global_load_lds(
            (const __attribute__((address_space(1))) void*)(ga[i]),
            (__attribute__((address_space(3))) void*)(la[i]), 16, 0, 0);
    #pragma unroll
    for (int i = 0; i < 2; ++i)
        __builtin_amdgcn_global_load_lds(
            (const __attribute__((address_space(1))) void*)(gb[i]),
            (__attribute__((address_space(3))) void*)(lb[i]), 16, 0, 0);
    __syncthreads();

    int cur = 0;
    #pragma unroll
    for (int kt = 0; kt < KDIM; kt += BK) {
        // Issue next tile's loads into the other buffer (flight ∥ compute).
        if (kt + BK < KDIM) {
            const int nxt = cur ^ 1;
            #pragma unroll
            for (int i = 0; i < 4; ++i)
                __builtin_amdgcn_global_load_lds(
                    (const __attribute__((address_space(1))) void*)(ga[i] + kt + BK),
                    (__attribute__((address_space(3))) void*)(la[i] + nxt * 16384),
                    16, 0, 0);
            #pragma unroll
            for (int i = 0; i < 2; ++i)
                __builtin_amdgcn_global_load_lds(
                    (const __attribute__((address_space(1))) void*)(gb[i] + kt + BK),
                    (__attribute__((address_space(3))) void*)(lb[i] + nxt * 8192),
                    16, 0, 0);
        }
        // Compute current buffer.
        const bf16_t* Abase = (const bf16_t*)As4 + cur * (BM * BK);
        const bf16_t* Bbase = (const bf16_t*)Bs4 + cur * (BN * BK);
        #pragma unroll
        for (int kk = 0; kk < BK; kk += 32) {
            bf16x8 af[4], bfv[2];
            #pragma unroll
            for (int i = 0; i < 4; ++i) {
                int m  = wm + i * 16 + fr_m;
                int cc = (kk >> 3) + fr_g;
                int sc = cc ^ (m & 7);
                af[i] = *(const bf16x8*)(Abase + m * BK + sc * 8);
            }
            #pragma unroll
            for (int j = 0; j < 2; ++j) {
                int n  = wn + j * 16 + fr_m;
                int cc = (kk >> 3) + fr_g;
                int sc = cc ^ (n & 7);
                bfv[j] = *(const bf16x8*)(Bbase + n * BK + sc * 8);
            }
            #pragma unroll
            for (int i = 0; i < 4; ++i)
                #pragma unroll
                for (int j = 0; j < 2; ++j)
                    acc[i][j] = __builtin_amdgcn_mfma_f32_16x16x32_bf16(
                        af[i], bfv[j], acc[i][j], 0, 0, 0);
        }
        __syncthreads();   // drains this wave's loads; all waves' reads done
        cur ^= 1;
    }

    // Epilogue: C/D layout col=lane&15, row=(lane>>4)*4+reg (m89-verified).
    #pragma unroll
    for (int i = 0; i < 4; ++i)
        #pragma unroll
        for (int j = 0; j < 2; ++j)
            #pragma unroll
            for (int r = 0; r < 4; ++r) {
                int rr = wm + i * 16 + fr_g * 4 + r;
                int cl = wn + j * 16 + fr_m;
                float v = acc[i][j][r];
                out[(size_t)(m0 + rr) * NDIM + (n0 + cl)] = (v > 1.0f) ? 1.0f : 0.0f;
            }
}

extern "C" void kernel_launch(void* const* d_in, const int* in_sizes, int n_in,
                              void* d_out, int out_size, void* d_ws, size_t ws_size,
                              hipStream_t stream) {
    (void)in_sizes; (void)n_in; (void)out_size; (void)ws_size;
    const float* u     = (const float*)d_in[0];
    const float* Lam   = (const float*)d_in[1];
    const float* lstep = (const float*)d_in[2];
    const float* Vre   = (const float*)d_in[3];
    const float* Vim   = (const float*)d_in[4];
    float* out = (float*)d_out;

    char* ws = (char*)d_ws;
    const size_t endv_bytes  = (size_t)NCHUNK * P_DIM * sizeof(float2);   // 2 MB
    const size_t carry_bytes = endv_bytes;                                // 2 MB
    const size_t bt_bytes    = (size_t)NDIM * KDIM * sizeof(bf16_t);      // 1 MB
    float2* endv  = (float2*)(ws);
    float2* carry = (float2*)(ws + endv_bytes);
    bf16_t* Bt    = (bf16_t*)(ws + endv_bytes + carry_bytes);
    bf16_t* A     = (bf16_t*)(ws + endv_bytes + carry_bytes + bt_bytes);  // 32 MB

    hipLaunchKernelGGL(k_scan_ends, dim3(NCHUNK), dim3(256), 0, stream,
                       u, Lam, lstep, Vre, Vim, endv, Bt);
    hipLaunchKernelGGL(k_carry, dim3(P_DIM / 2), dim3(1024), 0, stream,
                       Lam, lstep, endv, carry);
    hipLaunchKernelGGL(k_materialize, dim3(NCHUNK), dim3(256), 0, stream,
                       u, Lam, lstep, carry, A);
    hipLaunchKernelGGL(k_gemm, dim3(L_LEN / BM, NDIM / BN), dim3(256), 0, stream,
                       A, Bt, out);
}

// Round 9
// 134.514 us; speedup vs baseline: 1.1995x; 1.0348x over previous
//
#include <hip/hip_runtime.h>

#define L_LEN   16384
#define P_DIM   512
#define CHUNK   32
#define NCHUNK  512        // L_LEN / CHUNK

#define KDIM    1024       // 2*P, re/im interleaved: k = 2p (re), 2p+1 (im)
#define NDIM    512
#define BM      128
#define BN      64
#define BK      64

typedef __bf16 bf16_t;
typedef __bf16 bf16x8 __attribute__((ext_vector_type(8)));
typedef float  floatx4 __attribute__((ext_vector_type(4)));

__device__ __forceinline__ uint32_t pack_bf16(float a, float b) {
    bf16_t ha = (bf16_t)a, hb = (bf16_t)b;
    return (uint32_t)__builtin_bit_cast(unsigned short, ha)
         | ((uint32_t)__builtin_bit_cast(unsigned short, hb) << 16);
}

// Per-channel discretization constants: a = exp(lambda*step), B = (a-1)/lambda
__device__ __forceinline__ void ch_consts(float lam0, float lam1, float ls,
                                          float& ar, float& ai,
                                          float& br, float& bi) {
    float lr = -expf(lam0);               // Re(lambda) < 0
    float li = lam1;                      // Im(lambda)
    float s  = expf(ls);
    float er = expf(lr * s);
    ar = er * cosf(li * s);
    ai = er * sinf(li * s);
    float dr = ar - 1.0f, di = ai;
    float inv = 1.0f / (lr * lr + li * li);
    br = (dr * lr + di * li) * inv;
    bi = (di * lr - dr * li) * inv;
}

// Phase 1: per (chunk, channel-pair) local scan, zero init; write end states.
// Thread t handles channels 2t, 2t+1 via float2 loads. Bt pack fused in.
__global__ void __launch_bounds__(256) k_scan_ends(const float* __restrict__ u,
        const float* __restrict__ Lam, const float* __restrict__ lstep,
        const float* __restrict__ Vre, const float* __restrict__ Vim,
        float2* __restrict__ endv, bf16_t* __restrict__ Bt) {
    const int t = threadIdx.x;
    const int c = blockIdx.x;

    // Bt pack: Bt[j][2p]=V_re[j][p], Bt[j][2p+1]=-V_im[j][p]. idx covers 512*512/2.
    {
        int idx = c * 256 + t;
        float2 vr = ((const float2*)Vre)[idx];
        float2 vi = ((const float2*)Vim)[idx];
        ((uint2*)Bt)[idx] = make_uint2(pack_bf16(vr.x, -vi.x),
                                       pack_bf16(vr.y, -vi.y));
    }

    float4 lam4 = ((const float4*)Lam)[t];       // channels 2t, 2t+1
    float2 ls2  = ((const float2*)lstep)[t];
    float ar0, ai0, br0, bi0, ar1, ai1, br1, bi1;
    ch_consts(lam4.x, lam4.y, ls2.x, ar0, ai0, br0, bi0);
    ch_consts(lam4.z, lam4.w, ls2.y, ar1, ai1, br1, bi1);

    float xr0 = 0.f, xi0 = 0.f, xr1 = 0.f, xi1 = 0.f;
    const float2* up = (const float2*)(u + (size_t)c * CHUNK * P_DIM) + t;
    #pragma unroll 8
    for (int k = 0; k < CHUNK; ++k) {
        float2 uv = up[(size_t)k * (P_DIM / 2)];
        float nr0 = ar0 * xr0 - ai0 * xi0 + br0 * uv.x;
        float ni0 = ar0 * xi0 + ai0 * xr0 + bi0 * uv.x;
        float nr1 = ar1 * xr1 - ai1 * xi1 + br1 * uv.y;
        float ni1 = ar1 * xi1 + ai1 * xr1 + bi1 * uv.y;
        xr0 = nr0; xi0 = ni0; xr1 = nr1; xi1 = ni1;
    }
    ((float4*)endv)[c * 256 + t] = make_float4(xr0, xi0, xr1, xi1);
}

// Phase 2: Kogge-Stone carry scan over 512 chunk aggregates.
// Block = 2 channels x 512 chunks = 1024 threads; 256 blocks.
// carry[c] = state entering chunk c; A_chunk = a^CHUNK.
__global__ void __launch_bounds__(1024) k_carry(const float* __restrict__ Lam,
        const float* __restrict__ lstep, const float2* __restrict__ endv,
        float2* __restrict__ carry) {
    __shared__ float2 zl[NCHUNK * 2];
    const int tid = threadIdx.x;
    const int g = tid & 1;            // channel slot within block
    const int c = tid >> 1;           // chunk index 0..511
    const int p = blockIdx.x * 2 + g;

    float lr = -expf(Lam[2 * p + 0]);
    float li = Lam[2 * p + 1];
    float s  = expf(lstep[p]);
    float tt = s * (float)CHUNK;
    float er = expf(lr * tt);
    float Ar = er * cosf(li * tt);    // A = a^CHUNK
    float Ai = er * sinf(li * tt);

    float2 e = endv[(size_t)c * P_DIM + p];
    float zr = e.x, zi = e.y;
    zl[c * 2 + g] = make_float2(zr, zi);
    __syncthreads();
    for (int st = 1; st < NCHUNK; st <<= 1) {
        float tr = 0.f, ti = 0.f;
        if (c >= st) { float2 v = zl[(c - st) * 2 + g]; tr = v.x; ti = v.y; }
        __syncthreads();
        zr += Ar * tr - Ai * ti;
        zi += Ar * ti + Ai * tr;
        zl[c * 2 + g] = make_float2(zr, zi);
        float nAr = Ar * Ar - Ai * Ai;    // A^(2s)
        float nAi = 2.f * Ar * Ai;
        Ar = nAr; Ai = nAi;
        __syncthreads();
    }
    float2 cv = make_float2(0.f, 0.f);
    if (c > 0) cv = zl[(c - 1) * 2 + g];   // exclusive prefix
    carry[(size_t)c * P_DIM + p] = cv;
}

// Phase 3: recompute local scan with carry init; write A bf16 row-major
// [t][1024], k interleaved -> one 8B store per step per channel-pair.
__global__ void __launch_bounds__(256) k_materialize(const float* __restrict__ u,
        const float* __restrict__ Lam, const float* __restrict__ lstep,
        const float2* __restrict__ carry, bf16_t* __restrict__ A) {
    const int t = threadIdx.x;
    const int c = blockIdx.x;

    float4 lam4 = ((const float4*)Lam)[t];
    float2 ls2  = ((const float2*)lstep)[t];
    float ar0, ai0, br0, bi0, ar1, ai1, br1, bi1;
    ch_consts(lam4.x, lam4.y, ls2.x, ar0, ai0, br0, bi0);
    ch_consts(lam4.z, lam4.w, ls2.y, ar1, ai1, br1, bi1);

    float4 cv = ((const float4*)carry)[c * 256 + t];
    float xr0 = cv.x, xi0 = cv.y, xr1 = cv.z, xi1 = cv.w;
    const float2* up = (const float2*)(u + (size_t)c * CHUNK * P_DIM) + t;
    uint2* Ap = (uint2*)(A + (size_t)c * CHUNK * KDIM) + t;   // 256 uint2 per row
    #pragma unroll 4
    for (int k = 0; k < CHUNK; ++k) {
        float2 uv = up[(size_t)k * (P_DIM / 2)];
        float nr0 = ar0 * xr0 - ai0 * xi0 + br0 * uv.x;
        float ni0 = ar0 * xi0 + ai0 * xr0 + bi0 * uv.x;
        float nr1 = ar1 * xr1 - ai1 * xi1 + br1 * uv.y;
        float ni1 = ar1 * xi1 + ai1 * xr1 + bi1 * uv.y;
        xr0 = nr0; xi0 = ni0; xr1 = nr1; xi1 = ni1;
        Ap[(size_t)k * 256] = make_uint2(pack_bf16(xr0, xi0),
                                         pack_bf16(xr1, xi1));
    }
}

// GEMM with COUNTED-vmcnt 2-deep pipeline (T4, m218): tiles kt and kt+1 are
// always in flight; per iter {s_waitcnt vmcnt(6); s_barrier; compute buf[cur];
// s_barrier; stage kt+2 -> buf[cur]}. The counted wait releases exactly the
// older tile's 6 loads while the newer 6 stay in flight ACROSS the barriers
// (never drain to 0 in-loop). Raw s_barrier (no implicit vmcnt0 drain).
// Per-wave vmcnt audit: top-of-iter outstanding = 12 (tiles kt,kt+1); each
// wave stages its own LDS chunks, so vmcnt(6)+barrier => tile kt fully ready.
// Uniform control flow: every wave executes identical barrier count (no
// divergence-deadlock). Staging keeps rule-21 pair: LINEAR LDS dest,
// INVERSE-swizzled global source.
__global__ void __launch_bounds__(256, 3) k_gemm(const bf16_t* __restrict__ A,
        const bf16_t* __restrict__ Bt, float* __restrict__ out) {
    __shared__ uint4 As4[2 * BM * BK * 2 / 16];   // 2 x 1024 chunks, 32 KB
    __shared__ uint4 Bs4[2 * BN * BK * 2 / 16];   // 2 x  512 chunks, 16 KB

    const int tid  = threadIdx.x;
    const int lane = tid & 63;
    const int w    = tid >> 6;
    const int m0   = blockIdx.x * BM;
    const int n0   = blockIdx.y * BN;
    const int wm   = (w >> 1) * 64;   // 0 or 64
    const int wn   = (w & 1) * 32;    // 0 or 32

    const int fr_m = lane & 15;   // M/N index within 16x16 for A/B operands
    const int fr_g = lane >> 4;   // k-group (quad) 0..3

    floatx4 acc[4][2];
    #pragma unroll
    for (int i = 0; i < 4; ++i)
        #pragma unroll
        for (int j = 0; j < 2; ++j) {
            floatx4 z = {0.f, 0.f, 0.f, 0.f};
            acc[i][j] = z;
        }

    const bf16_t* Asrc = A  + (size_t)m0 * KDIM;
    const bf16_t* Bsrc = Bt + (size_t)n0 * KDIM;

    // Hoisted staging addresses. q = linear LDS chunk slot; source chunk
    // col = (q&7) ^ (row&7) so swizzled reads land right.
    const bf16_t* ga[4]; char* la[4];
    const bf16_t* gb[2]; char* lb[2];
    #pragma unroll
    for (int i = 0; i < 4; ++i) {
        int q   = i * 256 + tid;
        int row = q >> 3;
        int gc  = (q & 7) ^ (row & 7);
        ga[i] = Asrc + (size_t)row * KDIM + gc * 8;
        la[i] = (char*)As4 + (size_t)q * 16;
    }
    #pragma unroll
    for (int i = 0; i < 2; ++i) {
        int q   = i * 256 + tid;
        int row = q >> 3;
        int gc  = (q & 7) ^ (row & 7);
        gb[i] = Bsrc + (size_t)row * KDIM + gc * 8;
        lb[i] = (char*)Bs4 + (size_t)q * 16;
    }

#define STAGE(KT, BUF)                                                        \
    do {                                                                      \
        _Pragma("unroll")                                                     \
        for (int i_ = 0; i_ < 4; ++i_)                                        \
            __builtin_amdgcn_global_load_lds(                                 \
                (const __attribute__((address_space(1))) void*)(ga[i_] + (KT)),\
                (__attribute__((address_space(3))) void*)(la[i_] + (BUF) * 16384),\
                16, 0, 0);                                                    \
        _Pragma("unroll")                                                     \
        for (int i_ = 0; i_ < 2; ++i_)                                        \
            __builtin_amdgcn_global_load_lds(                                 \
                (const __attribute__((address_space(1))) void*)(gb[i_] + (KT)),\
                (__attribute__((address_space(3))) void*)(lb[i_] + (BUF) * 8192),\
                16, 0, 0);                                                    \
    } while (0)

#define COMPUTE(BUF)                                                          \
    do {                                                                      \
        const bf16_t* Abase = (const bf16_t*)As4 + (BUF) * (BM * BK);         \
        const bf16_t* Bbase = (const bf16_t*)Bs4 + (BUF) * (BN * BK);         \
        _Pragma("unroll")                                                     \
        for (int kk = 0; kk < BK; kk += 32) {                                 \
            bf16x8 af[4], bfv[2];                                             \
            _Pragma("unroll")                                                 \
            for (int i_ = 0; i_ < 4; ++i_) {                                  \
                int m  = wm + i_ * 16 + fr_m;                                 \
                int cc = (kk >> 3) + fr_g;                                    \
                int sc = cc ^ (m & 7);                                        \
                af[i_] = *(const bf16x8*)(Abase + m * BK + sc * 8);           \
            }                                                                 \
            _Pragma("unroll")                                                 \
            for (int j_ = 0; j_ < 2; ++j_) {                                  \
                int n  = wn + j_ * 16 + fr_m;                                 \
                int cc = (kk >> 3) + fr_g;                                    \
                int sc = cc ^ (n & 7);                                        \
                bfv[j_] = *(const bf16x8*)(Bbase + n * BK + sc * 8);          \
            }                                                                 \
            _Pragma("unroll")                                                 \
            for (int i_ = 0; i_ < 4; ++i_)                                    \
                _Pragma("unroll")                                             \
                for (int j_ = 0; j_ < 2; ++j_)                                \
                    acc[i_][j_] = __builtin_amdgcn_mfma_f32_16x16x32_bf16(    \
                        af[i_], bfv[j_], acc[i_][j_], 0, 0, 0);               \
        }                                                                     \
    } while (0)

    // Prologue: tiles 0 and 1 in flight (12 loads).
    STAGE(0, 0);
    STAGE(BK, 1);

    int cur = 0;
    for (int kt = 0; kt < KDIM - BK; kt += BK) {   // 15 iters; tile 15 peeled
        asm volatile("s_waitcnt vmcnt(6)" ::: "memory");
        __builtin_amdgcn_s_barrier();
        COMPUTE(cur);
        __builtin_amdgcn_s_barrier();
        if (kt + 2 * BK < KDIM)
            STAGE(kt + 2 * BK, cur);
        cur ^= 1;
    }
    // Last tile: only its 6 loads remain outstanding.
    asm volatile("s_waitcnt vmcnt(0)" ::: "memory");
    __builtin_amdgcn_s_barrier();
    COMPUTE(cur);

#undef STAGE
#undef COMPUTE

    // Epilogue: C/D layout col=lane&15, row=(lane>>4)*4+reg (m89-verified).
    #pragma unroll
    for (int i = 0; i < 4; ++i)
        #pragma unroll
        for (int j = 0; j < 2; ++j)
            #pragma unroll
            for (int r = 0; r < 4; ++r) {
                int rr = wm + i * 16 + fr_g * 4 + r;
                int cl = wn + j * 16 + fr_m;
                float v = acc[i][j][r];
                out[(size_t)(m0 + rr) * NDIM + (n0 + cl)] = (v > 1.0f) ? 1.0f : 0.0f;
            }
}

extern "C" void kernel_launch(void* const* d_in, const int* in_sizes, int n_in,
                              void* d_out, int out_size, void* d_ws, size_t ws_size,
                              hipStream_t stream) {
    (void)in_sizes; (void)n_in; (void)out_size; (void)ws_size;
    const float* u     = (const float*)d_in[0];
    const float* Lam   = (const float*)d_in[1];
    const float* lstep = (const float*)d_in[2];
    const float* Vre   = (const float*)d_in[3];
    const float* Vim   = (const float*)d_in[4];
    float* out = (float*)d_out;

    char* ws = (char*)d_ws;
    const size_t endv_bytes  = (size_t)NCHUNK * P_DIM * sizeof(float2);   // 2 MB
    const size_t carry_bytes = endv_bytes;                                // 2 MB
    const size_t bt_bytes    = (size_t)NDIM * KDIM * sizeof(bf16_t);      // 1 MB
    float2* endv  = (float2*)(ws);
    float2* carry = (float2*)(ws + endv_bytes);
    bf16_t* Bt    = (bf16_t*)(ws + endv_bytes + carry_bytes);
    bf16_t* A     = (bf16_t*)(ws + endv_bytes + carry_bytes + bt_bytes);  // 32 MB

    hipLaunchKernelGGL(k_scan_ends, dim3(NCHUNK), dim3(256), 0, stream,
                       u, Lam, lstep, Vre, Vim, endv, Bt);
    hipLaunchKernelGGL(k_carry, dim3(P_DIM / 2), dim3(1024), 0, stream,
                       Lam, lstep, endv, carry);
    hipLaunchKernelGGL(k_materialize, dim3(NCHUNK), dim3(256), 0, stream,
                       u, Lam, lstep, carry, A);
    hipLaunchKernelGGL(k_gemm, dim3(L_LEN / BM, NDIM / BN), dim3(256), 0, stream,
                       A, Bt, out);
}

// Round 10
// 127.489 us; speedup vs baseline: 1.2656x; 1.0551x over previous
//
#include <hip/hip_runtime.h>

#define L_LEN   16384
#define P_DIM   512
#define CHUNK   32
#define NCHUNK  512        // L_LEN / CHUNK

#define KDIM    1024       // 2*P, re/im interleaved: k = 2p (re), 2p+1 (im)
#define NDIM    512
#define BM      128
#define BN      64
#define BK      64

typedef __bf16 bf16_t;
typedef __bf16 bf16x8 __attribute__((ext_vector_type(8)));
typedef float  floatx4 __attribute__((ext_vector_type(4)));

__device__ __forceinline__ uint32_t pack_bf16(float a, float b) {
    bf16_t ha = (bf16_t)a, hb = (bf16_t)b;
    return (uint32_t)__builtin_bit_cast(unsigned short, ha)
         | ((uint32_t)__builtin_bit_cast(unsigned short, hb) << 16);
}

// Per-channel discretization constants: a = exp(lambda*step), B = (a-1)/lambda
__device__ __forceinline__ void ch_consts(float lam0, float lam1, float ls,
                                          float& ar, float& ai,
                                          float& br, float& bi) {
    float lr = -expf(lam0);               // Re(lambda) < 0
    float li = lam1;                      // Im(lambda)
    float s  = expf(ls);
    float er = expf(lr * s);
    ar = er * cosf(li * s);
    ai = er * sinf(li * s);
    float dr = ar - 1.0f, di = ai;
    float inv = 1.0f / (lr * lr + li * li);
    br = (dr * lr + di * li) * inv;
    bi = (di * lr - dr * li) * inv;
}

// Phase 1: per (chunk, channel-pair) local scan, zero init; write end states.
// Thread t handles channels 2t, 2t+1 via float2 loads. Bt pack fused in.
__global__ void __launch_bounds__(256) k_scan_ends(const float* __restrict__ u,
        const float* __restrict__ Lam, const float* __restrict__ lstep,
        const float* __restrict__ Vre, const float* __restrict__ Vim,
        float2* __restrict__ endv, bf16_t* __restrict__ Bt) {
    const int t = threadIdx.x;
    const int c = blockIdx.x;

    // Bt pack: Bt[j][2p]=V_re[j][p], Bt[j][2p+1]=-V_im[j][p]. idx covers 512*512/2.
    {
        int idx = c * 256 + t;
        float2 vr = ((const float2*)Vre)[idx];
        float2 vi = ((const float2*)Vim)[idx];
        ((uint2*)Bt)[idx] = make_uint2(pack_bf16(vr.x, -vi.x),
                                       pack_bf16(vr.y, -vi.y));
    }

    float4 lam4 = ((const float4*)Lam)[t];       // channels 2t, 2t+1
    float2 ls2  = ((const float2*)lstep)[t];
    float ar0, ai0, br0, bi0, ar1, ai1, br1, bi1;
    ch_consts(lam4.x, lam4.y, ls2.x, ar0, ai0, br0, bi0);
    ch_consts(lam4.z, lam4.w, ls2.y, ar1, ai1, br1, bi1);

    float xr0 = 0.f, xi0 = 0.f, xr1 = 0.f, xi1 = 0.f;
    const float2* up = (const float2*)(u + (size_t)c * CHUNK * P_DIM) + t;
    #pragma unroll 8
    for (int k = 0; k < CHUNK; ++k) {
        float2 uv = up[(size_t)k * (P_DIM / 2)];
        float nr0 = ar0 * xr0 - ai0 * xi0 + br0 * uv.x;
        float ni0 = ar0 * xi0 + ai0 * xr0 + bi0 * uv.x;
        float nr1 = ar1 * xr1 - ai1 * xi1 + br1 * uv.y;
        float ni1 = ar1 * xi1 + ai1 * xr1 + bi1 * uv.y;
        xr0 = nr0; xi0 = ni0; xr1 = nr1; xi1 = ni1;
    }
    ((float4*)endv)[c * 256 + t] = make_float4(xr0, xi0, xr1, xi1);
}

// Phase 2: Kogge-Stone carry scan over 512 chunk aggregates.
// Block = 2 channels x 512 chunks = 1024 threads; 256 blocks.
// carry[c] = state entering chunk c; A_chunk = a^CHUNK.
__global__ void __launch_bounds__(1024) k_carry(const float* __restrict__ Lam,
        const float* __restrict__ lstep, const float2* __restrict__ endv,
        float2* __restrict__ carry) {
    __shared__ float2 zl[NCHUNK * 2];
    const int tid = threadIdx.x;
    const int g = tid & 1;            // channel slot within block
    const int c = tid >> 1;           // chunk index 0..511
    const int p = blockIdx.x * 2 + g;

    float lr = -expf(Lam[2 * p + 0]);
    float li = Lam[2 * p + 1];
    float s  = expf(lstep[p]);
    float tt = s * (float)CHUNK;
    float er = expf(lr * tt);
    float Ar = er * cosf(li * tt);    // A = a^CHUNK
    float Ai = er * sinf(li * tt);

    float2 e = endv[(size_t)c * P_DIM + p];
    float zr = e.x, zi = e.y;
    zl[c * 2 + g] = make_float2(zr, zi);
    __syncthreads();
    for (int st = 1; st < NCHUNK; st <<= 1) {
        float tr = 0.f, ti = 0.f;
        if (c >= st) { float2 v = zl[(c - st) * 2 + g]; tr = v.x; ti = v.y; }
        __syncthreads();
        zr += Ar * tr - Ai * ti;
        zi += Ar * ti + Ai * tr;
        zl[c * 2 + g] = make_float2(zr, zi);
        float nAr = Ar * Ar - Ai * Ai;    // A^(2s)
        float nAi = 2.f * Ar * Ai;
        Ar = nAr; Ai = nAi;
        __syncthreads();
    }
    float2 cv = make_float2(0.f, 0.f);
    if (c > 0) cv = zl[(c - 1) * 2 + g];   // exclusive prefix
    carry[(size_t)c * P_DIM + p] = cv;
}

// Phase 3: recompute local scan with carry init; write A bf16 row-major
// [t][1024], k interleaved -> one 8B store per step per channel-pair.
__global__ void __launch_bounds__(256) k_materialize(const float* __restrict__ u,
        const float* __restrict__ Lam, const float* __restrict__ lstep,
        const float2* __restrict__ carry, bf16_t* __restrict__ A) {
    const int t = threadIdx.x;
    const int c = blockIdx.x;

    float4 lam4 = ((const float4*)Lam)[t];
    float2 ls2  = ((const float2*)lstep)[t];
    float ar0, ai0, br0, bi0, ar1, ai1, br1, bi1;
    ch_consts(lam4.x, lam4.y, ls2.x, ar0, ai0, br0, bi0);
    ch_consts(lam4.z, lam4.w, ls2.y, ar1, ai1, br1, bi1);

    float4 cv = ((const float4*)carry)[c * 256 + t];
    float xr0 = cv.x, xi0 = cv.y, xr1 = cv.z, xi1 = cv.w;
    const float2* up = (const float2*)(u + (size_t)c * CHUNK * P_DIM) + t;
    uint2* Ap = (uint2*)(A + (size_t)c * CHUNK * KDIM) + t;   // 256 uint2 per row
    #pragma unroll 4
    for (int k = 0; k < CHUNK; ++k) {
        float2 uv = up[(size_t)k * (P_DIM / 2)];
        float nr0 = ar0 * xr0 - ai0 * xi0 + br0 * uv.x;
        float ni0 = ar0 * xi0 + ai0 * xr0 + bi0 * uv.x;
        float nr1 = ar1 * xr1 - ai1 * xi1 + br1 * uv.y;
        float ni1 = ar1 * xi1 + ai1 * xr1 + bi1 * uv.y;
        xr0 = nr0; xi0 = ni0; xr1 = nr1; xi1 = ni1;
        Ap[(size_t)k * 256] = make_uint2(pack_bf16(xr0, xi0),
                                         pack_bf16(xr1, xi1));
    }
}

// GEMM: out[m][n] = sum_k A[m][k]*Bt[n][k], spike threshold epilogue.
// 128x64 block tile (grid 1024 = 4 blocks/CU for cross-block overlap),
// 4 waves each 64x32 (4x2 of 16x16x32 bf16 MFMA), BK=64.
// Staging via global_load_lds width=16: LINEAR LDS dest, INVERSE-swizzled
// global source, swizzled ds_read. LDS slot (row,sc) holds chunk (row, sc^(row&7)).
__global__ void __launch_bounds__(256, 4) k_gemm(const bf16_t* __restrict__ A,
        const bf16_t* __restrict__ Bt, float* __restrict__ out) {
    __shared__ uint4 As4[BM * BK * 2 / 16];   // 1024 chunks, 16 KB
    __shared__ uint4 Bs4[BN * BK * 2 / 16];   //  512 chunks,  8 KB

    const int tid  = threadIdx.x;
    const int lane = tid & 63;
    const int w    = tid >> 6;
    const int m0   = blockIdx.x * BM;
    const int n0   = blockIdx.y * BN;
    const int wm   = (w >> 1) * 64;   // 0 or 64
    const int wn   = (w & 1) * 32;    // 0 or 32

    const int fr_m = lane & 15;   // M/N index within 16x16 for A/B operands
    const int fr_g = lane >> 4;   // k-group (quad) 0..3

    floatx4 acc[4][2];
    #pragma unroll
    for (int i = 0; i < 4; ++i)
        #pragma unroll
        for (int j = 0; j < 2; ++j) {
            floatx4 z = {0.f, 0.f, 0.f, 0.f};
            acc[i][j] = z;
        }

    const bf16_t* Asrc = A  + (size_t)m0 * KDIM;
    const bf16_t* Bsrc = Bt + (size_t)n0 * KDIM;

    // Hoisted staging addresses. q = linear LDS chunk slot; source chunk
    // col = (q&7) ^ (row&7) so swizzled reads land right.
    const bf16_t* ga[4]; char* la[4];
    const bf16_t* gb[2]; char* lb[2];
    #pragma unroll
    for (int i = 0; i < 4; ++i) {
        int q   = i * 256 + tid;
        int row = q >> 3;
        int gc  = (q & 7) ^ (row & 7);
        ga[i] = Asrc + (size_t)row * KDIM + gc * 8;
        la[i] = (char*)As4 + (size_t)q * 16;
    }
    #pragma unroll
    for (int i = 0; i < 2; ++i) {
        int q   = i * 256 + tid;
        int row = q >> 3;
        int gc  = (q & 7) ^ (row & 7);
        gb[i] = Bsrc + (size_t)row * KDIM + gc * 8;
        lb[i] = (char*)Bs4 + (size_t)q * 16;
    }

    for (int kt = 0; kt < KDIM; kt += BK) {
        __syncthreads();   // prior reads of LDS done before overwrite
        #pragma unroll
        for (int i = 0; i < 4; ++i)
            __builtin_amdgcn_global_load_lds(
                (const __attribute__((address_space(1))) void*)(ga[i] + kt),
                (__attribute__((address_space(3))) void*)la[i], 16, 0, 0);
        #pragma unroll
        for (int i = 0; i < 2; ++i)
            __builtin_amdgcn_global_load_lds(
                (const __attribute__((address_space(1))) void*)(gb[i] + kt),
                (__attribute__((address_space(3))) void*)lb[i], 16, 0, 0);
        __syncthreads();   // drains vmcnt(0) then barrier: tile ready
        #pragma unroll
        for (int kk = 0; kk < BK; kk += 32) {
            bf16x8 af[4], bf[2];
            #pragma unroll
            for (int i = 0; i < 4; ++i) {
                int m  = wm + i * 16 + fr_m;
                int cc = (kk >> 3) + fr_g;
                int sc = cc ^ (m & 7);
                af[i] = *(const bf16x8*)((const bf16_t*)As4 + m * BK + sc * 8);
            }
            #pragma unroll
            for (int j = 0; j < 2; ++j) {
                int n  = wn + j * 16 + fr_m;
                int cc = (kk >> 3) + fr_g;
                int sc = cc ^ (n & 7);
                bf[j] = *(const bf16x8*)((const bf16_t*)Bs4 + n * BK + sc * 8);
            }
            #pragma unroll
            for (int i = 0; i < 4; ++i)
                #pragma unroll
                for (int j = 0; j < 2; ++j)
                    acc[i][j] = __builtin_amdgcn_mfma_f32_16x16x32_bf16(
                        af[i], bf[j], acc[i][j], 0, 0, 0);
        }
    }

    // Epilogue: C/D layout col=lane&15, row=(lane>>4)*4+reg (m89-verified).
    #pragma unroll
    for (int i = 0; i < 4; ++i)
        #pragma unroll
        for (int j = 0; j < 2; ++j)
            #pragma unroll
            for (int r = 0; r < 4; ++r) {
                int rr = wm + i * 16 + fr_g * 4 + r;
                int cl = wn + j * 16 + fr_m;
                float v = acc[i][j][r];
                out[(size_t)(m0 + rr) * NDIM + (n0 + cl)] = (v > 1.0f) ? 1.0f : 0.0f;
            }
}

extern "C" void kernel_launch(void* const* d_in, const int* in_sizes, int n_in,
                              void* d_out, int out_size, void* d_ws, size_t ws_size,
                              hipStream_t stream) {
    (void)in_sizes; (void)n_in; (void)out_size; (void)ws_size;
    const float* u     = (const float*)d_in[0];
    const float* Lam   = (const float*)d_in[1];
    const float* lstep = (const float*)d_in[2];
    const float* Vre   = (const float*)d_in[3];
    const float* Vim   = (const float*)d_in[4];
    float* out = (float*)d_out;

    char* ws = (char*)d_ws;
    const size_t endv_bytes  = (size_t)NCHUNK * P_DIM * sizeof(float2);   // 2 MB
    const size_t carry_bytes = endv_bytes;                                // 2 MB
    const size_t bt_bytes    = (size_t)NDIM * KDIM * sizeof(bf16_t);      // 1 MB
    float2* endv  = (float2*)(ws);
    float2* carry = (float2*)(ws + endv_bytes);
    bf16_t* Bt    = (bf16_t*)(ws + endv_bytes + carry_bytes);
    bf16_t* A     = (bf16_t*)(ws + endv_bytes + carry_bytes + bt_bytes);  // 32 MB

    hipLaunchKernelGGL(k_scan_ends, dim3(NCHUNK), dim3(256), 0, stream,
                       u, Lam, lstep, Vre, Vim, endv, Bt);
    hipLaunchKernelGGL(k_carry, dim3(P_DIM / 2), dim3(1024), 0, stream,
                       Lam, lstep, endv, carry);
    hipLaunchKernelGGL(k_materialize, dim3(NCHUNK), dim3(256), 0, stream,
                       u, Lam, lstep, carry, A);
    hipLaunchKernelGGL(k_gemm, dim3(L_LEN / BM, NDIM / BN), dim3(256), 0, stream,
                       A, Bt, out);
}